// Round 17
// baseline (47.953 us; speedup 1.0000x reference)
//
#include <hip/hip_runtime.h>
#include <hip/hip_bf16.h>

// Fused spatial self-attention, B=4 C=64 H=W=64 (N=4096), fp32 in/out.
// Round 17: R16 (best, 47.6us) + KVB 64->128: one barrier per 128 keys
// (half the barrier/vmcnt-drain frequency). K tile 128x64 (16KB), V tile
// 64x128 (16KB, 256B rows, swz byte^=(row&15)<<4), dbuf 64KB, 2 blocks/CU.
// Inner 64-key body (joint softmax, in-lane P via K-row bit2<->3 perm,
// threshold defer-rescale, setprio) unchanged and runs twice per tile.

using f16    = _Float16;
using f16x8  = __attribute__((ext_vector_type(8))) f16;
using f32x16 = __attribute__((ext_vector_type(16))) float;
using i32x4  = __attribute__((ext_vector_type(4))) int;

static constexpr int NB = 4;     // batch
static constexpr int NC = 64;    // channels
static constexpr int NT = 4096;  // tokens (H*W)
static constexpr int KVB = 128;  // keys per staged tile (2 x 64-key halves)
static constexpr float LOG2E = 1.44269504088896f;

__device__ __forceinline__ float fexp2(float x) { return __builtin_amdgcn_exp2f(x); }
__device__ __forceinline__ unsigned int pkrtz(float a, float b) {
    return __builtin_bit_cast(unsigned int, __builtin_amdgcn_cvt_pkrtz(a, b));
}
__device__ __forceinline__ void gload_lds16(const void* g, void* l) {
    __builtin_amdgcn_global_load_lds(
        (const __attribute__((address_space(1))) unsigned int*)g,
        (__attribute__((address_space(3))) unsigned int*)l, 16, 0, 0);
}

// ---------------- kernel 1: QKV projection (f16 MFMA) ----------------
// grid = 3 * B * (N/64); 4 waves x one 32x32 output tile.
__global__ __launch_bounds__(256) void qkv_proj(
    const float* __restrict__ x,
    const float* __restrict__ Wq, const float* __restrict__ bq,
    const float* __restrict__ Wk, const float* __restrict__ bk,
    const float* __restrict__ Wv, const float* __restrict__ bv,
    f16* __restrict__ qh, f16* __restrict__ kh, f16* __restrict__ vv)
{
    __shared__ f16 xT[64 * 64];   // [n][c], swz byte^=((n&7)<<4)
    __shared__ f16 wS[64 * 64];   // [o][c], swz byte^=((o&7)<<4)

    const int t  = threadIdx.x;
    const int p  = blockIdx.x >> 8;          // 0=q 1=k 2=v
    const int b  = (blockIdx.x >> 6) & 3;
    const int n0 = (blockIdx.x & 63) << 6;

    const float* Wp = (p == 0) ? Wq : (p == 1) ? Wk : Wv;
    const float* bp = (p == 0) ? bq : (p == 1) ? bk : bv;

    char* const xb = (char*)xT;
    char* const wb = (char*)wS;

    #pragma unroll
    for (int i = 0; i < 4; ++i) {
        const int idx = i * 256 + t;
        const int c = idx >> 4, n4 = (idx & 15) << 2;
        const float4 xv = *reinterpret_cast<const float4*>(
            x + ((size_t)(b * NC + c)) * NT + n0 + n4);
        const float xe[4] = {xv.x, xv.y, xv.z, xv.w};
        #pragma unroll
        for (int j = 0; j < 4; ++j) {
            const int n = n4 + j;
            *reinterpret_cast<f16*>(xb + n * 128 + ((c * 2) ^ ((n & 7) << 4))) =
                (f16)xe[j];
        }
        const int o = idx >> 4, c4 = (idx & 15) << 2;
        const float4 wv4 = *reinterpret_cast<const float4*>(Wp + o * 64 + c4);
        const uint2 pk = make_uint2(pkrtz(wv4.x, wv4.y), pkrtz(wv4.z, wv4.w));
        *reinterpret_cast<uint2*>(wb + o * 128 + ((c4 * 2) ^ ((o & 7) << 4))) = pk;
    }
    __syncthreads();

    const int lane = t & 63;
    const int wv   = t >> 6;
    const int l31  = lane & 31;
    const int hi   = lane >> 5;
    const int tr   = (wv & 1) << 5;   // tile rows
    const int tc   = (wv >> 1) << 5;  // tile cols

    f32x16 acc = {0,0,0,0,0,0,0,0,0,0,0,0,0,0,0,0};

    if (p < 2) {
        const int ra = tr + l31, rb = tc + l31;
        #pragma unroll
        for (int ks = 0; ks < 4; ++ks) {
            const int col = ks * 32 + hi * 16;
            const f16x8 a = *reinterpret_cast<const f16x8*>(
                xb + ra * 128 + (col ^ ((ra & 7) << 4)));
            const f16x8 bf = *reinterpret_cast<const f16x8*>(
                wb + rb * 128 + (col ^ ((rb & 7) << 4)));
            acc = __builtin_amdgcn_mfma_f32_32x32x16_f16(a, bf, acc, 0, 0, 0);
        }
        f16* hp = (p == 0) ? qh : kh;
        const float qs = (p == 0) ? LOG2E : 1.0f;
        const float bias = bp[tc + l31];
        #pragma unroll
        for (int r = 0; r < 16; ++r) {
            const int row = (r & 3) + 8 * (r >> 2) + 4 * hi;   // token
            hp[((size_t)(b * NT + n0 + tr + row)) * NC + tc + l31] =
                (f16)((acc[r] + bias) * qs);
        }
    } else {
        const int ra = tr + l31, rb = tc + l31;
        #pragma unroll
        for (int ks = 0; ks < 4; ++ks) {
            const int col = ks * 32 + hi * 16;
            const f16x8 a = *reinterpret_cast<const f16x8*>(
                wb + ra * 128 + (col ^ ((ra & 7) << 4)));
            const f16x8 bf = *reinterpret_cast<const f16x8*>(
                xb + rb * 128 + (col ^ ((rb & 7) << 4)));
            acc = __builtin_amdgcn_mfma_f32_32x32x16_f16(a, bf, acc, 0, 0, 0);
        }
        #pragma unroll
        for (int r = 0; r < 16; ++r) {
            const int row = (r & 3) + 8 * (r >> 2) + 4 * hi;   // out-ch
            vv[((size_t)(b * NC + tr + row)) * NT + n0 + tc + l31] =
                (f16)(acc[r] + bp[tr + row]);
        }
    }
}

// ---------------- kernel 2: flash attention (8-wave, KVB=128) -------------
// Block = 8 waves x 32 queries = 256 queries; grid = splits*NB*(NT/256).
__global__ __launch_bounds__(512, 4) void attn_fused(
    const f16* __restrict__ qh, const f16* __restrict__ kh,
    const f16* __restrict__ vv, float* __restrict__ out,
    f16* __restrict__ pacc, float* __restrict__ pm,
    float* __restrict__ pl, int nTiles, int direct)
{
    // Per buffer: K 128x64 f16 (16KB, 128B rows, swz (row&7)<<4) then
    //             V 64x128 f16 (16KB, 256B rows, swz (row&15)<<4).
    __shared__ f16 smem[2][2 * KVB * 64];    // 2 x 32KB

    const int t    = threadIdx.x;
    const int lane = t & 63;
    const int wv   = t >> 6;        // 0..7
    const int l31  = lane & 31;
    const int hi   = lane >> 5;

    // block decode (+ XCD-chunked swizzle when #groups % 8 == 0)
    const int ngrp = (int)gridDim.x >> 4;   // # (split,batch) groups
    int grp, i0;
    if ((ngrp & 7) == 0) {
        const int gpx  = ngrp >> 3;
        const int slot = (int)blockIdx.x >> 3;
        grp = ((int)blockIdx.x & 7) * gpx + (slot >> 4);
        i0  = (slot & 15) << 8;
    } else {
        grp = (int)blockIdx.x >> 4;
        i0  = ((int)blockIdx.x & 15) << 8;
    }
    const int s = grp >> 2;       // split index
    const int b = grp & 3;        // batch

    // Q B-fragments: lane holds Q[query = i0+wv*32+l31][ch = ks*16 + hi*8 + j]
    f16x8 qf[4];
    {
        const size_t qoff = ((size_t)(b * NT + i0 + wv * 32 + l31)) * NC + hi * 8;
        #pragma unroll
        for (int ks = 0; ks < 4; ++ks)
            qf[ks] = *reinterpret_cast<const f16x8*>(qh + qoff + ks * 16);
    }

    f32x16 acc0 = {0,0,0,0,0,0,0,0,0,0,0,0,0,0,0,0};
    f32x16 acc1 = {0,0,0,0,0,0,0,0,0,0,0,0,0,0,0,0};
    float m = -INFINITY, l = 0.f;   // per-lane (query l31; dup over hi)

    const f16* kh_g = kh + (size_t)b * NT * NC;
    const f16* v_g  = vv + (size_t)b * NC * NT;

    // DMA staging per 128-key tile: 32 x 1KB segments (16 K + 16 V), 4/wave.
    // K seg = 8 rows x 128B: row = seg*8 + (lane>>3), col inv-swz by (row&7).
    //   K rows PERMUTED (key bits 2<->3) so PV B-frags are in-lane.
    // V seg = 4 rows x 256B: row = vseg*4 + (lane>>4), col inv-swz by (row&15).
    const int srowK = lane >> 3;                         // 0..7
    const int scolK = (((lane & 7) ^ srowK) << 3);       // f16 col
    const int srowV = lane >> 4;                         // 0..3
    auto stage = [&](int j0, int buf) {
        f16* const base = &smem[buf][0];
        #pragma unroll
        for (int i = 0; i < 4; ++i) {
            const int idx = wv * 4 + i;      // 0..31
            if (idx < 16) {                  // K segment
                const int seg = idx;
                const int row = seg * 8 + srowK;
                const int krow = (row & ~12) | ((row & 4) << 1) | ((row & 8) >> 1);
                gload_lds16(kh_g + (size_t)(j0 + krow) * NC + scolK,
                            base + seg * 512 + lane * 8);
            } else {                         // V segment
                const int vseg = idx - 16;
                const int vrow = vseg * 4 + srowV;
                const int vcol = ((lane & 15) ^ (vrow & 15)) << 3;   // f16
                gload_lds16(v_g + (size_t)vrow * NT + j0 + vcol,
                            base + KVB * 64 + vseg * 512 + lane * 8);
            }
        }
    };

    const int t0 = s * nTiles;
    stage(t0 * KVB, 0);
    __syncthreads();   // drains vmcnt(0): buf0 ready

    for (int k = 0; k < nTiles; ++k) {
        if (k + 1 < nTiles) stage((t0 + k + 1) * KVB, (k + 1) & 1);

        char* const khsb = (char*)&smem[k & 1][0];
        char* const vsb  = khsb + KVB * 64 * 2;   // V region, bytes

        #pragma unroll
        for (int h = 0; h < 2; ++h) {        // two 64-key halves, no barrier
            // ---- S^T for both 32-key sub-blocks of this half ----
            f32x16 sS0 = {0,0,0,0,0,0,0,0,0,0,0,0,0,0,0,0};
            f32x16 sS1 = {0,0,0,0,0,0,0,0,0,0,0,0,0,0,0,0};
            __builtin_amdgcn_s_setprio(1);
            #pragma unroll
            for (int ks = 0; ks < 4; ++ks) {
                const int col = ks * 32 + hi * 16;
                const int r0 = h * 64 + l31;
                const f16x8 ak0 = *reinterpret_cast<const f16x8*>(
                    khsb + r0 * 128 + (col ^ ((r0 & 7) << 4)));
                sS0 = __builtin_amdgcn_mfma_f32_32x32x16_f16(ak0, qf[ks], sS0, 0, 0, 0);
                const int r1 = h * 64 + 32 + l31;
                const f16x8 ak1 = *reinterpret_cast<const f16x8*>(
                    khsb + r1 * 128 + (col ^ ((r1 & 7) << 4)));
                sS1 = __builtin_amdgcn_mfma_f32_32x32x16_f16(ak1, qf[ks], sS1, 0, 0, 0);
            }
            __builtin_amdgcn_s_setprio(0);
            // sS[8*ks + j] = P[query l31][key h*64 + kb*32 + 16*ks + 8*hi + j]

            // ---- joint softmax over 64 keys; threshold defer-rescale ----
            float mx[8];
            #pragma unroll
            for (int i = 0; i < 8; ++i)
                mx[i] = fmaxf(fmaxf(sS0[i], sS0[i + 8]), fmaxf(sS1[i], sS1[i + 8]));
            #pragma unroll
            for (int i = 0; i < 4; ++i) mx[i] = fmaxf(mx[i], mx[i + 4]);
            mx[0] = fmaxf(mx[0], mx[2]); mx[1] = fmaxf(mx[1], mx[3]);
            float mt = fmaxf(mx[0], mx[1]);
            mt = fmaxf(mt, __shfl_xor(mt, 32));

            const bool grow = __any(mt > m + 8.f);   // defer small max growth
            const float mn = grow ? fmaxf(m, mt) : m;

            float rs = 0.f;
            #pragma unroll
            for (int r = 0; r < 16; ++r) { sS0[r] = fexp2(sS0[r] - mn); rs += sS0[r]; }
            #pragma unroll
            for (int r = 0; r < 16; ++r) { sS1[r] = fexp2(sS1[r] - mn); rs += sS1[r]; }
            rs += __shfl_xor(rs, 32);

            if (grow) {
                const float sc = fexp2(m - mn);
                m = mn;
                l = l * sc + rs;
                #pragma unroll
                for (int r = 0; r < 16; ++r) { acc0[r] *= sc; acc1[r] *= sc; }
            } else {
                l += rs;
            }

            // ---- pack P in-lane + PV (V rows 256B, swz (row&15)<<4) ----
            auto pv_sub = [&](const f32x16& sX, int kb) {
                __builtin_amdgcn_s_setprio(1);
                #pragma unroll
                for (int ks = 0; ks < 2; ++ks) {
                    const unsigned int w0 = pkrtz(sX[8 * ks + 0], sX[8 * ks + 1]);
                    const unsigned int w1 = pkrtz(sX[8 * ks + 2], sX[8 * ks + 3]);
                    const unsigned int w2 = pkrtz(sX[8 * ks + 4], sX[8 * ks + 5]);
                    const unsigned int w3 = pkrtz(sX[8 * ks + 6], sX[8 * ks + 7]);
                    const i32x4 wv4 = {(int)w0, (int)w1, (int)w2, (int)w3};
                    const f16x8 bf = __builtin_bit_cast(f16x8, wv4);

                    const int vcol = h * 128 + kb * 64 + ks * 32 + hi * 16;
                    const int vrow0 = l31;
                    const f16x8 av0 = *reinterpret_cast<const f16x8*>(
                        vsb + vrow0 * 256 + (vcol ^ ((vrow0 & 15) << 4)));
                    acc0 = __builtin_amdgcn_mfma_f32_32x32x16_f16(av0, bf, acc0, 0, 0, 0);
                    const int vrow1 = 32 + l31;
                    const f16x8 av1 = *reinterpret_cast<const f16x8*>(
                        vsb + vrow1 * 256 + (vcol ^ ((vrow1 & 15) << 4)));
                    acc1 = __builtin_amdgcn_mfma_f32_32x32x16_f16(av1, bf, acc1, 0, 0, 0);
                }
                __builtin_amdgcn_s_setprio(0);
            };
            pv_sub(sS0, 0);
            pv_sub(sS1, 1);
        }

        __syncthreads();   // one barrier per 128 keys
    }

    // ---- epilogue: O[ch][query]; ch = cb*32 + (r&3)+8*(r>>2)+4*hi ----
    const int q = i0 + wv * 32 + l31;
    const float linv = 1.f / l;
    if (direct) {
        const size_t ob = (size_t)b * NC * NT;
        #pragma unroll
        for (int r = 0; r < 16; ++r) {
            const int ch = (r & 3) + 8 * (r >> 2) + 4 * hi;
            out[ob + (size_t)ch * NT + q]        = acc0[r] * linv;
            out[ob + (size_t)(32 + ch) * NT + q] = acc1[r] * linv;
        }
    } else {
        const size_t pb = (size_t)(s * NB + b);
        #pragma unroll
        for (int r = 0; r < 16; ++r) {
            const int ch = (r & 3) + 8 * (r >> 2) + 4 * hi;
            pacc[(pb * NC + ch) * NT + q]      = (f16)(acc0[r] * linv);
            pacc[(pb * NC + 32 + ch) * NT + q] = (f16)(acc1[r] * linv);
        }
        if (hi == 0) {
            pm[pb * NT + q] = m;
            pl[pb * NT + q] = l;
        }
    }
}

// ---------------- kernel 3: merge (vectorized, 8 outputs/thread) ----------
// grid = NB * 64 * 2 = 512 blocks.
__global__ __launch_bounds__(256) void merge_partials(
    const f16* __restrict__ pacc, const float* __restrict__ pm,
    const float* __restrict__ pl, float* __restrict__ out, int splits)
{
    const int t  = threadIdx.x;
    const int b  = blockIdx.x >> 7;
    const int c  = (blockIdx.x >> 1) & 63;
    const int i0 = ((((int)blockIdx.x & 1) << 8) + t) << 3;

    float M[8];
    #pragma unroll
    for (int j = 0; j < 8; ++j) M[j] = -INFINITY;
    for (int s = 0; s < splits; ++s) {
        const float* pmb = pm + (size_t)(s * NB + b) * NT + i0;
        const float4 a = *reinterpret_cast<const float4*>(pmb);
        const float4 d = *reinterpret_cast<const float4*>(pmb + 4);
        M[0] = fmaxf(M[0], a.x); M[1] = fmaxf(M[1], a.y);
        M[2] = fmaxf(M[2], a.z); M[3] = fmaxf(M[3], a.w);
        M[4] = fmaxf(M[4], d.x); M[5] = fmaxf(M[5], d.y);
        M[6] = fmaxf(M[6], d.z); M[7] = fmaxf(M[7], d.w);
    }
    float L[8] = {0,0,0,0,0,0,0,0}, A[8] = {0,0,0,0,0,0,0,0};
    for (int s = 0; s < splits; ++s) {
        const size_t pb = (size_t)(s * NB + b);
        const float* pmb = pm + pb * NT + i0;
        const float* plb = pl + pb * NT + i0;
        const float4 m0 = *reinterpret_cast<const float4*>(pmb);
        const float4 m1 = *reinterpret_cast<const float4*>(pmb + 4);
        const float4 l0 = *reinterpret_cast<const float4*>(plb);
        const float4 l1 = *reinterpret_cast<const float4*>(plb + 4);
        const f16x8 pv = *reinterpret_cast<const f16x8*>(
            pacc + (pb * NC + c) * NT + i0);
        const float me[8] = {m0.x, m0.y, m0.z, m0.w, m1.x, m1.y, m1.z, m1.w};
        const float le[8] = {l0.x, l0.y, l0.z, l0.w, l1.x, l1.y, l1.z, l1.w};
        #pragma unroll
        for (int j = 0; j < 8; ++j) {
            const float wl = fexp2(me[j] - M[j]) * le[j];
            L[j] += wl;
            A[j] += wl * (float)pv[j];
        }
    }
    float4 o0, o1;
    o0.x = A[0] / L[0]; o0.y = A[1] / L[1]; o0.z = A[2] / L[2]; o0.w = A[3] / L[3];
    o1.x = A[4] / L[4]; o1.y = A[5] / L[5]; o1.z = A[6] / L[6]; o1.w = A[7] / L[7];
    float* ob = out + ((size_t)b * NC + c) * NT + i0;
    *reinterpret_cast<float4*>(ob)     = o0;
    *reinterpret_cast<float4*>(ob + 4) = o1;
}

extern "C" void kernel_launch(void* const* d_in, const int* in_sizes, int n_in,
                              void* d_out, int out_size, void* d_ws, size_t ws_size,
                              hipStream_t stream)
{
    const float* x  = (const float*)d_in[0];
    const float* Wq = (const float*)d_in[1];
    const float* bq = (const float*)d_in[2];
    const float* Wk = (const float*)d_in[3];
    const float* bk = (const float*)d_in[4];
    const float* Wv = (const float*)d_in[5];
    const float* bv = (const float*)d_in[6];
    float* out = (float*)d_out;

    const size_t S = (size_t)NB * NT * NC;           // 1M elements
    const size_t base_bytes = 6 * S;                 // qh,kh,v fp16
    auto fits = [&](int sp) {
        return base_bytes + (size_t)sp * (2 * S + 2 * 4 * (size_t)NB * NT) <= ws_size;
    };
    const int splits = fits(8) ? 8 : fits(4) ? 4 : fits(2) ? 2 : fits(1) ? 1 : 0;

    f16* qh = (f16*)d_ws;
    f16* kh = qh + S;
    f16* vv = kh + S;

    qkv_proj<<<3 * NB * (NT / 64), 256, 0, stream>>>(x, Wq, bq, Wk, bk, Wv, bv,
                                                     qh, kh, vv);

    const int totTiles = NT / KVB;   // 32
    if (splits == 0) {
        attn_fused<<<NB * (NT / 256), 512, 0, stream>>>(
            qh, kh, vv, out, nullptr, nullptr, nullptr, totTiles, 1);
        return;
    }

    f16* pacc = vv + S;
    float* pm = (float*)(pacc + (size_t)splits * S);
    float* pl = pm + (size_t)splits * NB * NT;

    attn_fused<<<splits * NB * (NT / 256), 512, 0, stream>>>(
        qh, kh, vv, out, pacc, pm, pl, totTiles / splits, 0);
    merge_partials<<<NB * 128, 256, 0, stream>>>(pacc, pm, pl, out, splits);
}

// Round 19
// 47.140 us; speedup vs baseline: 1.0173x; 1.0173x over previous
//
#include <hip/hip_runtime.h>
#include <hip/hip_bf16.h>

// Fused spatial self-attention, B=4 C=64 H=W=64 (N=4096), fp32 in/out.
// Round 19: REVERT to R16 (best known, 47.56us) after R18's cooperative
// launch silently failed (output = poison; hipLaunchCooperativeKernel
// rejected the 512x512+32KB config). R16: 8-wave/512-thr attn blocks,
// launch_bounds(512,4), K-row bit2<->3 permutation (PV B-frags in-lane),
// joint 64-key softmax, threshold defer-rescale, one-barrier gload_lds
// dbuf, XCD-chunked grid, splits=8; MFMA qkv; vectorized merge.

using f16    = _Float16;
using f16x8  = __attribute__((ext_vector_type(8))) f16;
using f32x16 = __attribute__((ext_vector_type(16))) float;
using i32x4  = __attribute__((ext_vector_type(4))) int;

static constexpr int NB = 4;     // batch
static constexpr int NC = 64;    // channels
static constexpr int NT = 4096;  // tokens (H*W)
static constexpr int KVB = 64;   // keys per j-tile
static constexpr float LOG2E = 1.44269504088896f;

__device__ __forceinline__ float fexp2(float x) { return __builtin_amdgcn_exp2f(x); }
__device__ __forceinline__ unsigned int pkrtz(float a, float b) {
    return __builtin_bit_cast(unsigned int, __builtin_amdgcn_cvt_pkrtz(a, b));
}
__device__ __forceinline__ void gload_lds16(const void* g, void* l) {
    __builtin_amdgcn_global_load_lds(
        (const __attribute__((address_space(1))) unsigned int*)g,
        (__attribute__((address_space(3))) unsigned int*)l, 16, 0, 0);
}

// ---------------- kernel 1: QKV projection (f16 MFMA) ----------------
// grid = 3 * B * (N/64); 4 waves x one 32x32 output tile.
__global__ __launch_bounds__(256) void qkv_proj(
    const float* __restrict__ x,
    const float* __restrict__ Wq, const float* __restrict__ bq,
    const float* __restrict__ Wk, const float* __restrict__ bk,
    const float* __restrict__ Wv, const float* __restrict__ bv,
    f16* __restrict__ qh, f16* __restrict__ kh, f16* __restrict__ vv)
{
    __shared__ f16 xT[64 * 64];   // [n][c], swz byte^=((n&7)<<4)
    __shared__ f16 wS[64 * 64];   // [o][c], swz byte^=((o&7)<<4)

    const int t  = threadIdx.x;
    const int p  = blockIdx.x >> 8;          // 0=q 1=k 2=v
    const int b  = (blockIdx.x >> 6) & 3;
    const int n0 = (blockIdx.x & 63) << 6;

    const float* Wp = (p == 0) ? Wq : (p == 1) ? Wk : Wv;
    const float* bp = (p == 0) ? bq : (p == 1) ? bk : bv;

    char* const xb = (char*)xT;
    char* const wb = (char*)wS;

    #pragma unroll
    for (int i = 0; i < 4; ++i) {
        const int idx = i * 256 + t;
        const int c = idx >> 4, n4 = (idx & 15) << 2;
        const float4 xv = *reinterpret_cast<const float4*>(
            x + ((size_t)(b * NC + c)) * NT + n0 + n4);
        const float xe[4] = {xv.x, xv.y, xv.z, xv.w};
        #pragma unroll
        for (int j = 0; j < 4; ++j) {
            const int n = n4 + j;
            *reinterpret_cast<f16*>(xb + n * 128 + ((c * 2) ^ ((n & 7) << 4))) =
                (f16)xe[j];
        }
        const int o = idx >> 4, c4 = (idx & 15) << 2;
        const float4 wv4 = *reinterpret_cast<const float4*>(Wp + o * 64 + c4);
        const uint2 pk = make_uint2(pkrtz(wv4.x, wv4.y), pkrtz(wv4.z, wv4.w));
        *reinterpret_cast<uint2*>(wb + o * 128 + ((c4 * 2) ^ ((o & 7) << 4))) = pk;
    }
    __syncthreads();

    const int lane = t & 63;
    const int wv   = t >> 6;
    const int l31  = lane & 31;
    const int hi   = lane >> 5;
    const int tr   = (wv & 1) << 5;   // tile rows
    const int tc   = (wv >> 1) << 5;  // tile cols

    f32x16 acc = {0,0,0,0,0,0,0,0,0,0,0,0,0,0,0,0};

    if (p < 2) {
        const int ra = tr + l31, rb = tc + l31;
        #pragma unroll
        for (int ks = 0; ks < 4; ++ks) {
            const int col = ks * 32 + hi * 16;
            const f16x8 a = *reinterpret_cast<const f16x8*>(
                xb + ra * 128 + (col ^ ((ra & 7) << 4)));
            const f16x8 bf = *reinterpret_cast<const f16x8*>(
                wb + rb * 128 + (col ^ ((rb & 7) << 4)));
            acc = __builtin_amdgcn_mfma_f32_32x32x16_f16(a, bf, acc, 0, 0, 0);
        }
        f16* hp = (p == 0) ? qh : kh;
        const float qs = (p == 0) ? LOG2E : 1.0f;
        const float bias = bp[tc + l31];
        #pragma unroll
        for (int r = 0; r < 16; ++r) {
            const int row = (r & 3) + 8 * (r >> 2) + 4 * hi;   // token
            hp[((size_t)(b * NT + n0 + tr + row)) * NC + tc + l31] =
                (f16)((acc[r] + bias) * qs);
        }
    } else {
        const int ra = tr + l31, rb = tc + l31;
        #pragma unroll
        for (int ks = 0; ks < 4; ++ks) {
            const int col = ks * 32 + hi * 16;
            const f16x8 a = *reinterpret_cast<const f16x8*>(
                wb + ra * 128 + (col ^ ((ra & 7) << 4)));
            const f16x8 bf = *reinterpret_cast<const f16x8*>(
                xb + rb * 128 + (col ^ ((rb & 7) << 4)));
            acc = __builtin_amdgcn_mfma_f32_32x32x16_f16(a, bf, acc, 0, 0, 0);
        }
        #pragma unroll
        for (int r = 0; r < 16; ++r) {
            const int row = (r & 3) + 8 * (r >> 2) + 4 * hi;   // out-ch
            vv[((size_t)(b * NC + tr + row)) * NT + n0 + tc + l31] =
                (f16)(acc[r] + bp[tr + row]);
        }
    }
}

// ---------------- kernel 2: flash attention (8-wave, K-permuted) ----------
// Block = 8 waves x 32 queries = 256 queries; grid = splits*NB*(NT/256).
__global__ __launch_bounds__(512, 4) void attn_fused(
    const f16* __restrict__ qh, const f16* __restrict__ kh,
    const f16* __restrict__ vv, float* __restrict__ out,
    f16* __restrict__ pacc, float* __restrict__ pm,
    float* __restrict__ pl, int nTiles, int direct)
{
    // double-buffered, XOR-swizzled (byte ^= (row&7)<<4): K then V per buffer
    __shared__ f16 smem[2][2 * KVB * 64];    // 2 x 16KB

    const int t    = threadIdx.x;
    const int lane = t & 63;
    const int wv   = t >> 6;        // 0..7
    const int l31  = lane & 31;
    const int hi   = lane >> 5;

    // block decode (+ XCD-chunked swizzle when #groups % 8 == 0)
    const int ngrp = (int)gridDim.x >> 4;   // # (split,batch) groups
    int grp, i0;
    if ((ngrp & 7) == 0) {
        const int gpx  = ngrp >> 3;
        const int slot = (int)blockIdx.x >> 3;
        grp = ((int)blockIdx.x & 7) * gpx + (slot >> 4);
        i0  = (slot & 15) << 8;
    } else {
        grp = (int)blockIdx.x >> 4;
        i0  = ((int)blockIdx.x & 15) << 8;
    }
    const int s = grp >> 2;       // split index
    const int b = grp & 3;        // batch

    // Q B-fragments: lane holds Q[query = i0+wv*32+l31][ch = ks*16 + hi*8 + j]
    f16x8 qf[4];
    {
        const size_t qoff = ((size_t)(b * NT + i0 + wv * 32 + l31)) * NC + hi * 8;
        #pragma unroll
        for (int ks = 0; ks < 4; ++ks)
            qf[ks] = *reinterpret_cast<const f16x8*>(qh + qoff + ks * 16);
    }

    f32x16 acc0 = {0,0,0,0,0,0,0,0,0,0,0,0,0,0,0,0};
    f32x16 acc1 = {0,0,0,0,0,0,0,0,0,0,0,0,0,0,0,0};
    float m = -INFINITY, l = 0.f;   // per-lane (query l31; dup over hi)

    const f16* kh_g = kh + (size_t)b * NT * NC;
    const f16* v_g  = vv + (size_t)b * NC * NT;

    // DMA staging: 16 x 1KB segments per tile (8 K + 8 V), 2 per wave.
    // Linear LDS dest; source col inverse-swizzled so LDS holds
    // byte (row*128 + (colb ^ ((row&7)<<4))) = tile[row][colb].
    // K rows PERMUTED (key-index bits 2<->3 swapped) so S^T's D-layout holds
    // exactly the keys PV's B-frag needs in-lane (no shuffles).
    const int srow = (lane >> 3);                       // 0..7 within segment
    const int scol = (((lane & 7) ^ srow) << 3);        // f16 col, inv-swz
    auto stage = [&](int j0, int buf) {
        f16* const base = &smem[buf][0];
        #pragma unroll
        for (int i = 0; i < 2; ++i) {
            const int idx = wv * 2 + i;      // 0..15
            const int seg = idx & 7;
            const int row = seg * 8 + srow;
            f16* dst = base + (idx < 8 ? 0 : KVB * 64) + seg * 512 + (lane << 3);
            // swap bits 2<->3 of the key row index (K only)
            const int krow = (row & ~12) | ((row & 4) << 1) | ((row & 8) >> 1);
            const f16* src = (idx < 8)
                ? kh_g + (size_t)(j0 + krow) * NC + scol
                : v_g + (size_t)row * NT + j0 + scol;
            gload_lds16(src, dst);
        }
    };

    const int t0 = s * nTiles;
    stage(t0 * KVB, 0);
    __syncthreads();   // drains vmcnt(0): buf0 ready

    for (int k = 0; k < nTiles; ++k) {
        if (k + 1 < nTiles) stage((t0 + k + 1) * KVB, (k + 1) & 1);

        char* const khsb = (char*)&smem[k & 1][0];
        char* const vsb  = khsb + KVB * 64 * 2;   // bytes

        // ---- S^T for BOTH 32-key sub-blocks (independent MFMA chains) ----
        f32x16 sS0 = {0,0,0,0,0,0,0,0,0,0,0,0,0,0,0,0};
        f32x16 sS1 = {0,0,0,0,0,0,0,0,0,0,0,0,0,0,0,0};
        __builtin_amdgcn_s_setprio(1);
        #pragma unroll
        for (int ks = 0; ks < 4; ++ks) {
            const int col = ks * 32 + hi * 16;
            const int r0 = l31;
            const f16x8 ak0 = *reinterpret_cast<const f16x8*>(
                khsb + r0 * 128 + (col ^ ((r0 & 7) << 4)));
            sS0 = __builtin_amdgcn_mfma_f32_32x32x16_f16(ak0, qf[ks], sS0, 0, 0, 0);
            const int r1 = 32 + l31;
            const f16x8 ak1 = *reinterpret_cast<const f16x8*>(
                khsb + r1 * 128 + (col ^ ((r1 & 7) << 4)));
            sS1 = __builtin_amdgcn_mfma_f32_32x32x16_f16(ak1, qf[ks], sS1, 0, 0, 0);
        }
        __builtin_amdgcn_s_setprio(0);
        // sS[8*ks + j] = P[query l31][key kb*32 + 16*ks + 8*hi + j]

        // ---- joint softmax over 64 keys; threshold defer-rescale ----
        float mx[8];
        #pragma unroll
        for (int i = 0; i < 8; ++i)
            mx[i] = fmaxf(fmaxf(sS0[i], sS0[i + 8]), fmaxf(sS1[i], sS1[i + 8]));
        #pragma unroll
        for (int i = 0; i < 4; ++i) mx[i] = fmaxf(mx[i], mx[i + 4]);
        mx[0] = fmaxf(mx[0], mx[2]); mx[1] = fmaxf(mx[1], mx[3]);
        float mt = fmaxf(mx[0], mx[1]);
        mt = fmaxf(mt, __shfl_xor(mt, 32));

        const bool grow = __any(mt > m + 8.f);   // defer small max growth
        const float mn = grow ? fmaxf(m, mt) : m;

        float rs = 0.f;
        #pragma unroll
        for (int r = 0; r < 16; ++r) { sS0[r] = fexp2(sS0[r] - mn); rs += sS0[r]; }
        #pragma unroll
        for (int r = 0; r < 16; ++r) { sS1[r] = fexp2(sS1[r] - mn); rs += sS1[r]; }
        rs += __shfl_xor(rs, 32);

        if (grow) {
            const float sc = fexp2(m - mn);
            m = mn;
            l = l * sc + rs;
            #pragma unroll
            for (int r = 0; r < 16; ++r) { acc0[r] *= sc; acc1[r] *= sc; }
        } else {
            l += rs;
        }

        // ---- pack P in-lane (K-permutation makes B-frags local) + PV ----
        auto pv_sub = [&](const f32x16& sX, int kb) {
            __builtin_amdgcn_s_setprio(1);
            #pragma unroll
            for (int ks = 0; ks < 2; ++ks) {
                const unsigned int w0 = pkrtz(sX[8 * ks + 0], sX[8 * ks + 1]);
                const unsigned int w1 = pkrtz(sX[8 * ks + 2], sX[8 * ks + 3]);
                const unsigned int w2 = pkrtz(sX[8 * ks + 4], sX[8 * ks + 5]);
                const unsigned int w3 = pkrtz(sX[8 * ks + 6], sX[8 * ks + 7]);
                const i32x4 wv4 = {(int)w0, (int)w1, (int)w2, (int)w3};
                const f16x8 bf = __builtin_bit_cast(f16x8, wv4);

                const int vcol = kb * 64 + ks * 32 + hi * 16;   // byte col
                const int vrow0 = l31;
                const f16x8 av0 = *reinterpret_cast<const f16x8*>(
                    vsb + vrow0 * 128 + (vcol ^ ((vrow0 & 7) << 4)));
                acc0 = __builtin_amdgcn_mfma_f32_32x32x16_f16(av0, bf, acc0, 0, 0, 0);
                const int vrow1 = 32 + l31;
                const f16x8 av1 = *reinterpret_cast<const f16x8*>(
                    vsb + vrow1 * 128 + (vcol ^ ((vrow1 & 7) << 4)));
                acc1 = __builtin_amdgcn_mfma_f32_32x32x16_f16(av1, bf, acc1, 0, 0, 0);
            }
            __builtin_amdgcn_s_setprio(0);
        };
        pv_sub(sS0, 0);
        pv_sub(sS1, 1);

        __syncthreads();   // one barrier/tile: drains vmcnt -> next buf ready
    }

    // ---- epilogue: O[ch][query]; ch = cb*32 + (r&3)+8*(r>>2)+4*hi ----
    const int q = i0 + wv * 32 + l31;
    const float linv = 1.f / l;
    if (direct) {
        const size_t ob = (size_t)b * NC * NT;
        #pragma unroll
        for (int r = 0; r < 16; ++r) {
            const int ch = (r & 3) + 8 * (r >> 2) + 4 * hi;
            out[ob + (size_t)ch * NT + q]        = acc0[r] * linv;
            out[ob + (size_t)(32 + ch) * NT + q] = acc1[r] * linv;
        }
    } else {
        const size_t pb = (size_t)(s * NB + b);
        #pragma unroll
        for (int r = 0; r < 16; ++r) {
            const int ch = (r & 3) + 8 * (r >> 2) + 4 * hi;
            pacc[(pb * NC + ch) * NT + q]      = (f16)(acc0[r] * linv);
            pacc[(pb * NC + 32 + ch) * NT + q] = (f16)(acc1[r] * linv);
        }
        if (hi == 0) {
            pm[pb * NT + q] = m;
            pl[pb * NT + q] = l;
        }
    }
}

// ---------------- kernel 3: merge (vectorized, 8 outputs/thread) ----------
// grid = NB * 64 * 2 = 512 blocks.
__global__ __launch_bounds__(256) void merge_partials(
    const f16* __restrict__ pacc, const float* __restrict__ pm,
    const float* __restrict__ pl, float* __restrict__ out, int splits)
{
    const int t  = threadIdx.x;
    const int b  = blockIdx.x >> 7;
    const int c  = (blockIdx.x >> 1) & 63;
    const int i0 = ((((int)blockIdx.x & 1) << 8) + t) << 3;

    float M[8];
    #pragma unroll
    for (int j = 0; j < 8; ++j) M[j] = -INFINITY;
    for (int s = 0; s < splits; ++s) {
        const float* pmb = pm + (size_t)(s * NB + b) * NT + i0;
        const float4 a = *reinterpret_cast<const float4*>(pmb);
        const float4 d = *reinterpret_cast<const float4*>(pmb + 4);
        M[0] = fmaxf(M[0], a.x); M[1] = fmaxf(M[1], a.y);
        M[2] = fmaxf(M[2], a.z); M[3] = fmaxf(M[3], a.w);
        M[4] = fmaxf(M[4], d.x); M[5] = fmaxf(M[5], d.y);
        M[6] = fmaxf(M[6], d.z); M[7] = fmaxf(M[7], d.w);
    }
    float L[8] = {0,0,0,0,0,0,0,0}, A[8] = {0,0,0,0,0,0,0,0};
    for (int s = 0; s < splits; ++s) {
        const size_t pb = (size_t)(s * NB + b);
        const float* pmb = pm + pb * NT + i0;
        const float* plb = pl + pb * NT + i0;
        const float4 m0 = *reinterpret_cast<const float4*>(pmb);
        const float4 m1 = *reinterpret_cast<const float4*>(pmb + 4);
        const float4 l0 = *reinterpret_cast<const float4*>(plb);
        const float4 l1 = *reinterpret_cast<const float4*>(plb + 4);
        const f16x8 pv = *reinterpret_cast<const f16x8*>(
            pacc + (pb * NC + c) * NT + i0);
        const float me[8] = {m0.x, m0.y, m0.z, m0.w, m1.x, m1.y, m1.z, m1.w};
        const float le[8] = {l0.x, l0.y, l0.z, l0.w, l1.x, l1.y, l1.z, l1.w};
        #pragma unroll
        for (int j = 0; j < 8; ++j) {
            const float wl = fexp2(me[j] - M[j]) * le[j];
            L[j] += wl;
            A[j] += wl * (float)pv[j];
        }
    }
    float4 o0, o1;
    o0.x = A[0] / L[0]; o0.y = A[1] / L[1]; o0.z = A[2] / L[2]; o0.w = A[3] / L[3];
    o1.x = A[4] / L[4]; o1.y = A[5] / L[5]; o1.z = A[6] / L[6]; o1.w = A[7] / L[7];
    float* ob = out + ((size_t)b * NC + c) * NT + i0;
    *reinterpret_cast<float4*>(ob)     = o0;
    *reinterpret_cast<float4*>(ob + 4) = o1;
}

extern "C" void kernel_launch(void* const* d_in, const int* in_sizes, int n_in,
                              void* d_out, int out_size, void* d_ws, size_t ws_size,
                              hipStream_t stream)
{
    const float* x  = (const float*)d_in[0];
    const float* Wq = (const float*)d_in[1];
    const float* bq = (const float*)d_in[2];
    const float* Wk = (const float*)d_in[3];
    const float* bk = (const float*)d_in[4];
    const float* Wv = (const float*)d_in[5];
    const float* bv = (const float*)d_in[6];
    float* out = (float*)d_out;

    const size_t S = (size_t)NB * NT * NC;           // 1M elements
    const size_t base_bytes = 6 * S;                 // qh,kh,v fp16
    auto fits = [&](int sp) {
        return base_bytes + (size_t)sp * (2 * S + 2 * 4 * (size_t)NB * NT) <= ws_size;
    };
    const int splits = fits(8) ? 8 : fits(4) ? 4 : fits(2) ? 2 : fits(1) ? 1 : 0;

    f16* qh = (f16*)d_ws;
    f16* kh = qh + S;
    f16* vv = kh + S;

    qkv_proj<<<3 * NB * (NT / 64), 256, 0, stream>>>(x, Wq, bq, Wk, bk, Wv, bv,
                                                     qh, kh, vv);

    const int totTiles = NT / KVB;   // 64
    if (splits == 0) {
        attn_fused<<<NB * (NT / 256), 512, 0, stream>>>(
            qh, kh, vv, out, nullptr, nullptr, nullptr, totTiles, 1);
        return;
    }

    f16* pacc = vv + S;
    float* pm = (float*)(pacc + (size_t)splits * S);
    float* pl = pm + (size_t)splits * NB * NT;

    attn_fused<<<splits * NB * (NT / 256), 512, 0, stream>>>(
        qh, kh, vv, out, pacc, pm, pl, totTiles / splits, 0);
    merge_partials<<<NB * 128, 256, 0, stream>>>(pacc, pm, pl, out, splits);
}